// Round 15
// baseline (157.029 us; speedup 1.0000x reference)
//
#include <hip/hip_runtime.h>

#define H 128
#define RBITS 8
#define RR 256               // nodes per bucket (1<<RBITS)
#define NBIN 512             // bins (>= NB)
#define PACK_SHIFT 24        // pack = src | (dlow << 24); src < 2^24, dlow < 2^8
#define TS 4096              // edges per block in bucketB
#define CAP 6144             // padded capacity per bucket (mean 4096 + 32 sigma)
#define SRCCAP 6400          // group-kernel LDS src buffer (>= CAP)

__device__ __forceinline__ int lower_bound_i(const int* __restrict__ a, int n, int v) {
    int lo = 0, hi = n;
    while (lo < hi) { int m = (lo + hi) >> 1; if (a[m] < v) lo = m + 1; else hi = m; }
    return lo;
}

// bf16 helpers (round-to-nearest-even pack, cheap unpack)
__device__ __forceinline__ unsigned bf16pack(float a, float b) {
    unsigned ua = __float_as_uint(a), ub = __float_as_uint(b);
    ua += 0x7fffu + ((ua >> 16) & 1u);
    ub += 0x7fffu + ((ub >> 16) & 1u);
    return (ua >> 16) | (ub & 0xffff0000u);
}
__device__ __forceinline__ float bflo(unsigned u) { return __uint_as_float(u << 16); }
__device__ __forceinline__ float bfhi(unsigned u) { return __uint_as_float(u & 0xffff0000u); }

// ---- pass 1: histogram -> reserve chunk -> direct placement (dst cached in LDS) ----
__global__ __launch_bounds__(512) void bucketB_kernel(const int* __restrict__ ei, int E,
                                                      int* __restrict__ cursor,
                                                      unsigned* __restrict__ pairs) {
    __shared__ int hist[NBIN], loff[NBIN], gch[NBIN];
    __shared__ int dcache[TS];
    int t = threadIdx.x;
    int e0 = blockIdx.x * TS;
    int e1 = e0 + TS < E ? e0 + TS : E;
    int m = e1 - e0;
    hist[t] = 0;
    __syncthreads();
    for (int i = t; i < m; i += 512) {
        int d = ei[E + e0 + i];
        dcache[i] = d;
        atomicAdd(&hist[((unsigned)d) >> RBITS], 1);
    }
    __syncthreads();
    {
        int v = hist[t];
        loff[t] = 0;
        gch[t] = (v > 0) ? (t * CAP + atomicAdd(&cursor[t], v)) : 0;
    }
    __syncthreads();
    for (int i = t; i < m; i += 512) {
        unsigned d = (unsigned)dcache[i];
        unsigned s = (unsigned)ei[e0 + i];
        int b = d >> RBITS;
        int pos = atomicAdd(&loff[b], 1);
        int gp = gch[b] + pos;
        if (gp < (b + 1) * CAP)   // overflow guard (never taken at these stats)
            pairs[gp] = s | ((d & (RR - 1)) << PACK_SHIFT);
    }
}

// ---- pass 2: per-bucket grouping; emits dis, xp, rps/rpe, csr (coalesced) ----
__global__ __launch_bounds__(256) void group_kernel(const unsigned* __restrict__ pairs,
                                                    const int* __restrict__ cursor,
                                                    const float* __restrict__ x,
                                                    int N,
                                                    float* __restrict__ dis,
                                                    uint4* __restrict__ xp,
                                                    int* __restrict__ rps,
                                                    int* __restrict__ rpe,
                                                    int* __restrict__ csr) {
    __shared__ int cntl[RR], woffl[RR];
    __shared__ int sA[RR], sB[RR];
    __shared__ unsigned srcbuf[SRCCAP];
    int b = blockIdx.x, t = threadIdx.x;
    int lo = b * RR;
    int nn = (N - lo < RR) ? (N - lo) : RR;
    int start = b * CAP;
    int cnt = cursor[b];
    if (cnt > CAP) cnt = CAP;
    cntl[t] = 0;
    __syncthreads();
    for (int i = t; i < cnt; i += 256)
        atomicAdd(&cntl[pairs[start + i] >> PACK_SHIFT], 1);
    __syncthreads();
    // inclusive scan over 256
    sA[t] = cntl[t];
    __syncthreads();
    int* cur = sA; int* nxt = sB;
    for (int off = 1; off < 256; off <<= 1) {
        int v = cur[t];
        if (t >= off) v += cur[t - off];
        nxt[t] = v;
        __syncthreads();
        int* tmp = cur; cur = nxt; nxt = tmp;
    }
    if (t < nn) {
        int c = cntl[t];
        float dd = rsqrtf((float)c + 1.0f);
        dis[lo + t] = dd;
        int excl = cur[t] - c;
        rps[lo + t] = start + excl;
        rpe[lo + t] = start + excl + c;
        woffl[t] = excl;
        // fused xp write: bf16(x * dis), padded to 8
        const float* xr = x + (size_t)(lo + t) * 6;
        uint4 o;
        o.x = bf16pack(xr[0] * dd, xr[1] * dd);
        o.y = bf16pack(xr[2] * dd, xr[3] * dd);
        o.z = bf16pack(xr[4] * dd, xr[5] * dd);
        o.w = 0u;
        xp[lo + t] = o;
    }
    __syncthreads();
    bool fits = (cnt <= SRCCAP);
    for (int i = t; i < cnt; i += 256) {
        unsigned p = pairs[start + i];
        int dlow = p >> PACK_SHIFT;
        unsigned s = p & ((1u << PACK_SHIFT) - 1);
        int pos = atomicAdd(&woffl[dlow], 1);
        if (fits) srcbuf[pos] = s;
        else csr[start + pos] = (int)s;      // safety fallback
    }
    __syncthreads();
    if (fits)
        for (int i = t; i < cnt; i += 256) csr[start + i] = (int)srcbuf[i];
}

// ---- fused layer 1: 1-lane/node uint4 gather + 6->128 GEMM + relu + dis scale ----
__global__ __launch_bounds__(256) void l1_kernel(const int* __restrict__ rps,
                                                 const int* __restrict__ rpe,
                                                 const float* __restrict__ dis,
                                                 const int* __restrict__ csr,
                                                 const uint4* __restrict__ xp,
                                                 const float* __restrict__ W1,
                                                 const float* __restrict__ b1,
                                                 unsigned* __restrict__ hs, int N) {
    __shared__ float w[6 * H];
    __shared__ float bsh[H];
    __shared__ float axl[256][7];   // [node][feat0..5, dis]; stride 7 -> 2-way alias (free)
    int t = threadIdx.x;
    for (int i = t; i < 6 * H; i += 256) w[i] = W1[i];
    if (t < H) bsh[t] = b1[t];
    int node = blockIdx.x * 256 + t;
    if (node < N) {
        int j0 = rps[node], j1 = rpe[node];
        uint4 sv = xp[node];
        float a0 = bflo(sv.x), a1 = bfhi(sv.x), a2 = bflo(sv.y),
              a3 = bfhi(sv.y), a4 = bflo(sv.z), a5 = bfhi(sv.z);
        int j = j0;
        for (; j + 4 <= j1; j += 4) {
            uint4 v0 = xp[csr[j]];
            uint4 v1 = xp[csr[j + 1]];
            uint4 v2 = xp[csr[j + 2]];
            uint4 v3 = xp[csr[j + 3]];
            a0 += (bflo(v0.x) + bflo(v1.x)) + (bflo(v2.x) + bflo(v3.x));
            a1 += (bfhi(v0.x) + bfhi(v1.x)) + (bfhi(v2.x) + bfhi(v3.x));
            a2 += (bflo(v0.y) + bflo(v1.y)) + (bflo(v2.y) + bflo(v3.y));
            a3 += (bfhi(v0.y) + bfhi(v1.y)) + (bfhi(v2.y) + bfhi(v3.y));
            a4 += (bflo(v0.z) + bflo(v1.z)) + (bflo(v2.z) + bflo(v3.z));
            a5 += (bfhi(v0.z) + bfhi(v1.z)) + (bfhi(v2.z) + bfhi(v3.z));
        }
        for (; j < j1; ++j) {
            uint4 v = xp[csr[j]];
            a0 += bflo(v.x); a1 += bfhi(v.x); a2 += bflo(v.y);
            a3 += bfhi(v.y); a4 += bflo(v.z); a5 += bfhi(v.z);
        }
        float dd = dis[node];
        axl[t][0] = a0 * dd; axl[t][1] = a1 * dd; axl[t][2] = a2 * dd;
        axl[t][3] = a3 * dd; axl[t][4] = a4 * dd; axl[t][5] = a5 * dd;
        axl[t][6] = dd;
    }
    __syncthreads();
    int c = t & 3, nl_in = t >> 2;   // 4 lanes x 64 nodes per sub-tile
    for (int sub = 0; sub < 4; ++sub) {
        int nl = sub * 64 + nl_in;
        int gnode = blockIdx.x * 256 + nl;
        if (gnode < N) {
            float x0 = axl[nl][0], x1 = axl[nl][1], x2 = axl[nl][2],
                  x3 = axl[nl][3], x4 = axl[nl][4], x5 = axl[nl][5];
            float dd = axl[nl][6];
            unsigned* hr = hs + (size_t)gnode * 64;
            #pragma unroll
            for (int i = 0; i < 16; ++i) {
                int f = 8 * i + 2 * c;
                float o0 = bsh[f]     + x0 * w[f]           + x1 * w[H + f]       + x2 * w[2*H + f]
                                      + x3 * w[3*H + f]     + x4 * w[4*H + f]     + x5 * w[5*H + f];
                float o1 = bsh[f + 1] + x0 * w[f + 1]       + x1 * w[H + f + 1]   + x2 * w[2*H + f + 1]
                                      + x3 * w[3*H + f + 1] + x4 * w[4*H + f + 1] + x5 * w[5*H + f + 1];
                hr[4 * i + c] = bf16pack(fmaxf(o0, 0.f) * dd, fmaxf(o1, 0.f) * dd);
            }
        }
    }
}

#define ACC8(v) do { \
    acc0 += bflo((v).x); acc1 += bfhi((v).x); \
    acc2 += bflo((v).y); acc3 += bfhi((v).y); \
    acc4 += bflo((v).z); acc5 += bfhi((v).z); \
    acc6 += bflo((v).w); acc7 += bfhi((v).w); } while (0)

// ---- aggZ[d] = bf16( dis[d]*(hs[d] + sum hs[s]) ) ; 16 lanes/node, barrier-free ----
// launch_bounds(256,4): 64-VGPR budget so all 8 gather loads stay in flight
// (with (256,8) the 32-VGPR cap forced serialized ~4-load batches).
__global__ __launch_bounds__(256, 4) void aggz_kernel(const int* __restrict__ rps,
                                                      const int* __restrict__ rpe,
                                                      const int* __restrict__ csr,
                                                      const float* __restrict__ dis,
                                                      const uint4* __restrict__ hs,
                                                      uint4* __restrict__ out, int N) {
    int node = blockIdx.x * 16 + (threadIdx.x >> 4);
    if (node >= N) return;
    int c = threadIdx.x & 15;
    int j0 = rps[node], j1 = rpe[node];
    uint4 sv = hs[(size_t)node * 16 + c];
    float acc0 = bflo(sv.x), acc1 = bfhi(sv.x), acc2 = bflo(sv.y), acc3 = bfhi(sv.y),
          acc4 = bflo(sv.z), acc5 = bfhi(sv.z), acc6 = bflo(sv.w), acc7 = bfhi(sv.w);
    int j = j0;
    for (; j + 8 <= j1; j += 8) {
        int s0 = csr[j], s1 = csr[j+1], s2 = csr[j+2], s3 = csr[j+3];
        int s4 = csr[j+4], s5 = csr[j+5], s6 = csr[j+6], s7 = csr[j+7];
        uint4 v0 = hs[(size_t)s0 * 16 + c];
        uint4 v1 = hs[(size_t)s1 * 16 + c];
        uint4 v2 = hs[(size_t)s2 * 16 + c];
        uint4 v3 = hs[(size_t)s3 * 16 + c];
        uint4 v4 = hs[(size_t)s4 * 16 + c];
        uint4 v5 = hs[(size_t)s5 * 16 + c];
        uint4 v6 = hs[(size_t)s6 * 16 + c];
        uint4 v7 = hs[(size_t)s7 * 16 + c];
        ACC8(v0); ACC8(v1); ACC8(v2); ACC8(v3);
        ACC8(v4); ACC8(v5); ACC8(v6); ACC8(v7);
    }
    for (; j < j1; ++j) {
        uint4 v = hs[(size_t)csr[j] * 16 + c];
        ACC8(v);
    }
    float dd = dis[node];
    uint4 o;
    o.x = bf16pack(acc0 * dd, acc1 * dd);
    o.y = bf16pack(acc2 * dd, acc3 * dd);
    o.z = bf16pack(acc4 * dd, acc5 * dd);
    o.w = bf16pack(acc6 * dd, acc7 * dd);
    out[(size_t)node * 16 + c] = o;
}

// ---- pool: one 64-lane wave per graph, 4 graphs/block; lane u = feats (2u,2u+1) ----
__global__ __launch_bounds__(256) void pool_kernel(const unsigned* __restrict__ aggz,
                                                   const int* __restrict__ batch,
                                                   float* __restrict__ pmean,
                                                   int* __restrict__ pcnt, int N, int G) {
    int g = blockIdx.x * 4 + (threadIdx.x >> 6);
    if (g >= G) return;
    int lane = threadIdx.x & 63;
    int start = lower_bound_i(batch, N, g);
    int end   = lower_bound_i(batch, N, g + 1);
    float a0 = 0.f, a1 = 0.f;
    int n = start;
    for (; n + 4 <= end; n += 4) {
        unsigned v0 = aggz[(size_t)(n    ) * 64 + lane];
        unsigned v1 = aggz[(size_t)(n + 1) * 64 + lane];
        unsigned v2 = aggz[(size_t)(n + 2) * 64 + lane];
        unsigned v3 = aggz[(size_t)(n + 3) * 64 + lane];
        a0 += (bflo(v0) + bflo(v1)) + (bflo(v2) + bflo(v3));
        a1 += (bfhi(v0) + bfhi(v1)) + (bfhi(v2) + bfhi(v3));
    }
    for (; n < end; ++n) {
        unsigned v = aggz[(size_t)n * 64 + lane];
        a0 += bflo(v); a1 += bfhi(v);
    }
    int cnt = end - start;
    float inv = (cnt > 0) ? 1.f / (float)cnt : 0.f;
    *(float2*)(pmean + (size_t)g * H + 2 * lane) = make_float2(a0 * inv, a1 * inv);
    if (lane == 0) pcnt[g] = cnt;
}

// ---- out: 2 graphs per block IN PARALLEL (thread = one (g,f)); W2 in 64KB LDS ----
__global__ __launch_bounds__(256) void out_kernel(const float* __restrict__ pmean,
                                                  const int* __restrict__ pcnt,
                                                  const float* __restrict__ W2,
                                                  const float* __restrict__ b2,
                                                  float* __restrict__ out, int G) {
    __shared__ float w[H * H];   // exactly 64 KB
    int t = threadIdx.x;
    {
        const float4* W4 = (const float4*)W2;
        float4* wl = (float4*)w;
        for (int i = t; i < H * H / 4; i += 256) wl[i] = W4[i];
    }
    __syncthreads();
    int gi = t >> 7, f = t & 127;
    int g = blockIdx.x * 2 + gi;
    if (g >= G) return;
    if (pcnt[g] == 0) { out[(size_t)g * H + f] = 0.f; return; }
    const float* pr = pmean + (size_t)g * H;   // broadcast reads, L1/L2-cached
    float o = b2[f];
    #pragma unroll 8
    for (int k = 0; k < H; ++k) o += pr[k] * w[k * H + f];
    out[(size_t)g * H + f] = o;
}

extern "C" void kernel_launch(void* const* d_in, const int* in_sizes, int n_in,
                              void* d_out, int out_size, void* d_ws, size_t ws_size,
                              hipStream_t stream) {
    const float* x   = (const float*)d_in[0];
    const int*   ei  = (const int*)d_in[1];
    const int*   bat = (const int*)d_in[2];
    const float* W1  = (const float*)d_in[4];
    const float* b1  = (const float*)d_in[5];
    const float* W2  = (const float*)d_in[6];
    const float* b2  = (const float*)d_in[7];
    float* out = (float*)d_out;

    int N = in_sizes[0] / 6;
    int E = in_sizes[1] / 2;
    int G = out_size / H;
    int NB = (N + RR - 1) / RR;          // buckets (<= NBIN)

    char* ws = (char*)d_ws;
    size_t off = 0;
    auto carve = [&](size_t bytes) { void* p = ws + off; off = (off + bytes + 255) & ~(size_t)255; return p; };
    int*      cursor = (int*)  carve((size_t)NBIN * 4);
    float*    dis    = (float*)carve((size_t)N * 4);
    int*      rps    = (int*)  carve((size_t)N * 4);
    int*      rpe    = (int*)  carve((size_t)N * 4);
    int*      csr    = (int*)  carve((size_t)NB * CAP * 4);   // padded buckets
    unsigned* hs     = (unsigned*)carve((size_t)N * H * 2);   // bf16 packed
    uint4*    aggz   = (uint4*)carve((size_t)N * H * 2);      // bf16 packed
    uint4*    xp     = (uint4*)carve((size_t)N * 16);
    unsigned* pairs  = (unsigned*)carve((size_t)NB * CAP * 4);
    float*    pmean  = (float*)carve((size_t)G * H * 4);
    int*      pcnt   = (int*)  carve((size_t)G * 4);

    hipMemsetAsync(cursor, 0, (size_t)NBIN * 4, stream);

    // CSR build: histogram+reserve+place, then per-bucket grouping
    bucketB_kernel<<<(E + TS - 1) / TS, 512, 0, stream>>>(ei, E, cursor, pairs);
    group_kernel<<<NB, 256, 0, stream>>>(pairs, cursor, x, N, dis, xp, rps, rpe, csr);

    // layer 1 fused: gather + GEMM + relu + scale -> hs (bf16)
    l1_kernel<<<(N + 255) / 256, 256, 0, stream>>>(rps, rpe, dis, csr, xp, W1, b1, hs, N);

    // layer 2 aggregation (barrier-free gather, relaxed VGPR budget) -> aggz
    aggz_kernel<<<(N + 15) / 16, 256, 0, stream>>>(rps, rpe, csr, dis, (const uint4*)hs, aggz, N);

    // pool (1 wave/graph) + final GEMM (2 graphs/block, parallel)
    pool_kernel<<<(G + 3) / 4, 256, 0, stream>>>((const unsigned*)aggz, bat, pmean, pcnt, N, G);
    out_kernel<<<(G + 1) / 2, 256, 0, stream>>>(pmean, pcnt, W2, b2, out, G);
}

// Round 16
// 154.542 us; speedup vs baseline: 1.0161x; 1.0161x over previous
//
#include <hip/hip_runtime.h>

#define H 128
#define RBITS 8
#define RR 256               // nodes per bucket (1<<RBITS)
#define NBIN 512             // bins (>= NB)
#define PACK_SHIFT 24        // pack = src | (dlow << 24); src < 2^24, dlow < 2^8
#define TS 4096              // edges per block in bucketB
#define CAP 6144             // padded capacity per bucket (mean 4096 + 32 sigma)
#define SRCCAP 6400          // group-kernel LDS src buffer (>= CAP)

__device__ __forceinline__ int lower_bound_i(const int* __restrict__ a, int n, int v) {
    int lo = 0, hi = n;
    while (lo < hi) { int m = (lo + hi) >> 1; if (a[m] < v) lo = m + 1; else hi = m; }
    return lo;
}

// bf16 helpers (round-to-nearest-even pack, cheap unpack)
__device__ __forceinline__ unsigned bf16pack(float a, float b) {
    unsigned ua = __float_as_uint(a), ub = __float_as_uint(b);
    ua += 0x7fffu + ((ua >> 16) & 1u);
    ub += 0x7fffu + ((ub >> 16) & 1u);
    return (ua >> 16) | (ub & 0xffff0000u);
}
__device__ __forceinline__ float bflo(unsigned u) { return __uint_as_float(u << 16); }
__device__ __forceinline__ float bfhi(unsigned u) { return __uint_as_float(u & 0xffff0000u); }

// ---- pass 1: histogram -> reserve chunk -> direct placement (dst cached in LDS) ----
__global__ __launch_bounds__(512) void bucketB_kernel(const int* __restrict__ ei, int E,
                                                      int* __restrict__ cursor,
                                                      unsigned* __restrict__ pairs) {
    __shared__ int hist[NBIN], loff[NBIN], gch[NBIN];
    __shared__ int dcache[TS];
    int t = threadIdx.x;
    int e0 = blockIdx.x * TS;
    int e1 = e0 + TS < E ? e0 + TS : E;
    int m = e1 - e0;
    hist[t] = 0;
    __syncthreads();
    for (int i = t; i < m; i += 512) {
        int d = ei[E + e0 + i];
        dcache[i] = d;
        atomicAdd(&hist[((unsigned)d) >> RBITS], 1);
    }
    __syncthreads();
    {
        int v = hist[t];
        loff[t] = 0;
        gch[t] = (v > 0) ? (t * CAP + atomicAdd(&cursor[t], v)) : 0;
    }
    __syncthreads();
    for (int i = t; i < m; i += 512) {
        unsigned d = (unsigned)dcache[i];
        unsigned s = (unsigned)ei[e0 + i];
        int b = d >> RBITS;
        int pos = atomicAdd(&loff[b], 1);
        int gp = gch[b] + pos;
        if (gp < (b + 1) * CAP)   // overflow guard (never taken at these stats)
            pairs[gp] = s | ((d & (RR - 1)) << PACK_SHIFT);
    }
}

// ---- pass 2: per-bucket grouping; emits dis, xp, rps/rpe, csr (coalesced) ----
__global__ __launch_bounds__(256) void group_kernel(const unsigned* __restrict__ pairs,
                                                    const int* __restrict__ cursor,
                                                    const float* __restrict__ x,
                                                    int N,
                                                    float* __restrict__ dis,
                                                    uint4* __restrict__ xp,
                                                    int* __restrict__ rps,
                                                    int* __restrict__ rpe,
                                                    int* __restrict__ csr) {
    __shared__ int cntl[RR], woffl[RR];
    __shared__ int sA[RR], sB[RR];
    __shared__ unsigned srcbuf[SRCCAP];
    int b = blockIdx.x, t = threadIdx.x;
    int lo = b * RR;
    int nn = (N - lo < RR) ? (N - lo) : RR;
    int start = b * CAP;
    int cnt = cursor[b];
    if (cnt > CAP) cnt = CAP;
    cntl[t] = 0;
    __syncthreads();
    for (int i = t; i < cnt; i += 256)
        atomicAdd(&cntl[pairs[start + i] >> PACK_SHIFT], 1);
    __syncthreads();
    // inclusive scan over 256
    sA[t] = cntl[t];
    __syncthreads();
    int* cur = sA; int* nxt = sB;
    for (int off = 1; off < 256; off <<= 1) {
        int v = cur[t];
        if (t >= off) v += cur[t - off];
        nxt[t] = v;
        __syncthreads();
        int* tmp = cur; cur = nxt; nxt = tmp;
    }
    if (t < nn) {
        int c = cntl[t];
        float dd = rsqrtf((float)c + 1.0f);
        dis[lo + t] = dd;
        int excl = cur[t] - c;
        rps[lo + t] = start + excl;
        rpe[lo + t] = start + excl + c;
        woffl[t] = excl;
        // fused xp write: bf16(x * dis), padded to 8
        const float* xr = x + (size_t)(lo + t) * 6;
        uint4 o;
        o.x = bf16pack(xr[0] * dd, xr[1] * dd);
        o.y = bf16pack(xr[2] * dd, xr[3] * dd);
        o.z = bf16pack(xr[4] * dd, xr[5] * dd);
        o.w = 0u;
        xp[lo + t] = o;
    }
    __syncthreads();
    bool fits = (cnt <= SRCCAP);
    for (int i = t; i < cnt; i += 256) {
        unsigned p = pairs[start + i];
        int dlow = p >> PACK_SHIFT;
        unsigned s = p & ((1u << PACK_SHIFT) - 1);
        int pos = atomicAdd(&woffl[dlow], 1);
        if (fits) srcbuf[pos] = s;
        else csr[start + pos] = (int)s;      // safety fallback
    }
    __syncthreads();
    if (fits)
        for (int i = t; i < cnt; i += 256) csr[start + i] = (int)srcbuf[i];
}

// ---- fused layer 1: 1-lane/node uint4 gather + 6->128 GEMM + relu + dis scale ----
__global__ __launch_bounds__(256) void l1_kernel(const int* __restrict__ rps,
                                                 const int* __restrict__ rpe,
                                                 const float* __restrict__ dis,
                                                 const int* __restrict__ csr,
                                                 const uint4* __restrict__ xp,
                                                 const float* __restrict__ W1,
                                                 const float* __restrict__ b1,
                                                 unsigned* __restrict__ hs, int N) {
    __shared__ float w[6 * H];
    __shared__ float bsh[H];
    __shared__ float axl[256][7];   // [node][feat0..5, dis]; stride 7 -> 2-way alias (free)
    int t = threadIdx.x;
    for (int i = t; i < 6 * H; i += 256) w[i] = W1[i];
    if (t < H) bsh[t] = b1[t];
    int node = blockIdx.x * 256 + t;
    if (node < N) {
        int j0 = rps[node], j1 = rpe[node];
        uint4 sv = xp[node];
        float a0 = bflo(sv.x), a1 = bfhi(sv.x), a2 = bflo(sv.y),
              a3 = bfhi(sv.y), a4 = bflo(sv.z), a5 = bfhi(sv.z);
        int j = j0;
        for (; j + 4 <= j1; j += 4) {
            uint4 v0 = xp[csr[j]];
            uint4 v1 = xp[csr[j + 1]];
            uint4 v2 = xp[csr[j + 2]];
            uint4 v3 = xp[csr[j + 3]];
            a0 += (bflo(v0.x) + bflo(v1.x)) + (bflo(v2.x) + bflo(v3.x));
            a1 += (bfhi(v0.x) + bfhi(v1.x)) + (bfhi(v2.x) + bfhi(v3.x));
            a2 += (bflo(v0.y) + bflo(v1.y)) + (bflo(v2.y) + bflo(v3.y));
            a3 += (bfhi(v0.y) + bfhi(v1.y)) + (bfhi(v2.y) + bfhi(v3.y));
            a4 += (bflo(v0.z) + bflo(v1.z)) + (bflo(v2.z) + bflo(v3.z));
            a5 += (bfhi(v0.z) + bfhi(v1.z)) + (bfhi(v2.z) + bfhi(v3.z));
        }
        for (; j < j1; ++j) {
            uint4 v = xp[csr[j]];
            a0 += bflo(v.x); a1 += bfhi(v.x); a2 += bflo(v.y);
            a3 += bfhi(v.y); a4 += bflo(v.z); a5 += bfhi(v.z);
        }
        float dd = dis[node];
        axl[t][0] = a0 * dd; axl[t][1] = a1 * dd; axl[t][2] = a2 * dd;
        axl[t][3] = a3 * dd; axl[t][4] = a4 * dd; axl[t][5] = a5 * dd;
        axl[t][6] = dd;
    }
    __syncthreads();
    int c = t & 3, nl_in = t >> 2;   // 4 lanes x 64 nodes per sub-tile
    for (int sub = 0; sub < 4; ++sub) {
        int nl = sub * 64 + nl_in;
        int gnode = blockIdx.x * 256 + nl;
        if (gnode < N) {
            float x0 = axl[nl][0], x1 = axl[nl][1], x2 = axl[nl][2],
                  x3 = axl[nl][3], x4 = axl[nl][4], x5 = axl[nl][5];
            float dd = axl[nl][6];
            unsigned* hr = hs + (size_t)gnode * 64;
            #pragma unroll
            for (int i = 0; i < 16; ++i) {
                int f = 8 * i + 2 * c;
                float o0 = bsh[f]     + x0 * w[f]           + x1 * w[H + f]       + x2 * w[2*H + f]
                                      + x3 * w[3*H + f]     + x4 * w[4*H + f]     + x5 * w[5*H + f];
                float o1 = bsh[f + 1] + x0 * w[f + 1]       + x1 * w[H + f + 1]   + x2 * w[2*H + f + 1]
                                      + x3 * w[3*H + f + 1] + x4 * w[4*H + f + 1] + x5 * w[5*H + f + 1];
                hr[4 * i + c] = bf16pack(fmaxf(o0, 0.f) * dd, fmaxf(o1, 0.f) * dd);
            }
        }
    }
}

#define ACC8(v) do { \
    acc0 += bflo((v).x); acc1 += bfhi((v).x); \
    acc2 += bflo((v).y); acc3 += bfhi((v).y); \
    acc4 += bflo((v).z); acc5 += bfhi((v).z); \
    acc6 += bflo((v).w); acc7 += bfhi((v).w); } while (0)

// ---- aggZ[d] = bf16( dis[d]*(hs[d] + sum hs[s]) ) ; 16 lanes/node, barrier-free ----
// (256,8): 28-VGPR schedule, ~22 waves/CU — measured best (R14 62.4us); the
// relaxed (256,4)/44-VGPR variant regressed to 65.5us (TLP-bound, not ILP-bound).
__global__ __launch_bounds__(256, 8) void aggz_kernel(const int* __restrict__ rps,
                                                      const int* __restrict__ rpe,
                                                      const int* __restrict__ csr,
                                                      const float* __restrict__ dis,
                                                      const uint4* __restrict__ hs,
                                                      uint4* __restrict__ out, int N) {
    int node = blockIdx.x * 16 + (threadIdx.x >> 4);
    if (node >= N) return;
    int c = threadIdx.x & 15;
    int j0 = rps[node], j1 = rpe[node];
    uint4 sv = hs[(size_t)node * 16 + c];
    float acc0 = bflo(sv.x), acc1 = bfhi(sv.x), acc2 = bflo(sv.y), acc3 = bfhi(sv.y),
          acc4 = bflo(sv.z), acc5 = bfhi(sv.z), acc6 = bflo(sv.w), acc7 = bfhi(sv.w);
    int j = j0;
    for (; j + 8 <= j1; j += 8) {
        int s0 = csr[j], s1 = csr[j+1], s2 = csr[j+2], s3 = csr[j+3];
        int s4 = csr[j+4], s5 = csr[j+5], s6 = csr[j+6], s7 = csr[j+7];
        uint4 v0 = hs[(size_t)s0 * 16 + c];
        uint4 v1 = hs[(size_t)s1 * 16 + c];
        uint4 v2 = hs[(size_t)s2 * 16 + c];
        uint4 v3 = hs[(size_t)s3 * 16 + c];
        uint4 v4 = hs[(size_t)s4 * 16 + c];
        uint4 v5 = hs[(size_t)s5 * 16 + c];
        uint4 v6 = hs[(size_t)s6 * 16 + c];
        uint4 v7 = hs[(size_t)s7 * 16 + c];
        ACC8(v0); ACC8(v1); ACC8(v2); ACC8(v3);
        ACC8(v4); ACC8(v5); ACC8(v6); ACC8(v7);
    }
    for (; j < j1; ++j) {
        uint4 v = hs[(size_t)csr[j] * 16 + c];
        ACC8(v);
    }
    float dd = dis[node];
    uint4 o;
    o.x = bf16pack(acc0 * dd, acc1 * dd);
    o.y = bf16pack(acc2 * dd, acc3 * dd);
    o.z = bf16pack(acc4 * dd, acc5 * dd);
    o.w = bf16pack(acc6 * dd, acc7 * dd);
    out[(size_t)node * 16 + c] = o;
}

// ---- pool: one 64-lane wave per graph, 4 graphs/block; lane u = feats (2u,2u+1) ----
__global__ __launch_bounds__(256) void pool_kernel(const unsigned* __restrict__ aggz,
                                                   const int* __restrict__ batch,
                                                   float* __restrict__ pmean,
                                                   int* __restrict__ pcnt, int N, int G) {
    int g = blockIdx.x * 4 + (threadIdx.x >> 6);
    if (g >= G) return;
    int lane = threadIdx.x & 63;
    int start = lower_bound_i(batch, N, g);
    int end   = lower_bound_i(batch, N, g + 1);
    float a0 = 0.f, a1 = 0.f;
    int n = start;
    for (; n + 4 <= end; n += 4) {
        unsigned v0 = aggz[(size_t)(n    ) * 64 + lane];
        unsigned v1 = aggz[(size_t)(n + 1) * 64 + lane];
        unsigned v2 = aggz[(size_t)(n + 2) * 64 + lane];
        unsigned v3 = aggz[(size_t)(n + 3) * 64 + lane];
        a0 += (bflo(v0) + bflo(v1)) + (bflo(v2) + bflo(v3));
        a1 += (bfhi(v0) + bfhi(v1)) + (bfhi(v2) + bfhi(v3));
    }
    for (; n < end; ++n) {
        unsigned v = aggz[(size_t)n * 64 + lane];
        a0 += bflo(v); a1 += bfhi(v);
    }
    int cnt = end - start;
    float inv = (cnt > 0) ? 1.f / (float)cnt : 0.f;
    *(float2*)(pmean + (size_t)g * H + 2 * lane) = make_float2(a0 * inv, a1 * inv);
    if (lane == 0) pcnt[g] = cnt;
}

// ---- out: 2 graphs per block IN PARALLEL (thread = one (g,f)); W2 in 64KB LDS ----
__global__ __launch_bounds__(256) void out_kernel(const float* __restrict__ pmean,
                                                  const int* __restrict__ pcnt,
                                                  const float* __restrict__ W2,
                                                  const float* __restrict__ b2,
                                                  float* __restrict__ out, int G) {
    __shared__ float w[H * H];   // exactly 64 KB
    int t = threadIdx.x;
    {
        const float4* W4 = (const float4*)W2;
        float4* wl = (float4*)w;
        for (int i = t; i < H * H / 4; i += 256) wl[i] = W4[i];
    }
    __syncthreads();
    int gi = t >> 7, f = t & 127;
    int g = blockIdx.x * 2 + gi;
    if (g >= G) return;
    if (pcnt[g] == 0) { out[(size_t)g * H + f] = 0.f; return; }
    const float* pr = pmean + (size_t)g * H;   // broadcast reads, L1/L2-cached
    float o = b2[f];
    #pragma unroll 8
    for (int k = 0; k < H; ++k) o += pr[k] * w[k * H + f];
    out[(size_t)g * H + f] = o;
}

extern "C" void kernel_launch(void* const* d_in, const int* in_sizes, int n_in,
                              void* d_out, int out_size, void* d_ws, size_t ws_size,
                              hipStream_t stream) {
    const float* x   = (const float*)d_in[0];
    const int*   ei  = (const int*)d_in[1];
    const int*   bat = (const int*)d_in[2];
    const float* W1  = (const float*)d_in[4];
    const float* b1  = (const float*)d_in[5];
    const float* W2  = (const float*)d_in[6];
    const float* b2  = (const float*)d_in[7];
    float* out = (float*)d_out;

    int N = in_sizes[0] / 6;
    int E = in_sizes[1] / 2;
    int G = out_size / H;
    int NB = (N + RR - 1) / RR;          // buckets (<= NBIN)

    char* ws = (char*)d_ws;
    size_t off = 0;
    auto carve = [&](size_t bytes) { void* p = ws + off; off = (off + bytes + 255) & ~(size_t)255; return p; };
    int*      cursor = (int*)  carve((size_t)NBIN * 4);
    float*    dis    = (float*)carve((size_t)N * 4);
    int*      rps    = (int*)  carve((size_t)N * 4);
    int*      rpe    = (int*)  carve((size_t)N * 4);
    int*      csr    = (int*)  carve((size_t)NB * CAP * 4);   // padded buckets
    unsigned* hs     = (unsigned*)carve((size_t)N * H * 2);   // bf16 packed
    uint4*    aggz   = (uint4*)carve((size_t)N * H * 2);      // bf16 packed
    uint4*    xp     = (uint4*)carve((size_t)N * 16);
    unsigned* pairs  = (unsigned*)carve((size_t)NB * CAP * 4);
    float*    pmean  = (float*)carve((size_t)G * H * 4);
    int*      pcnt   = (int*)  carve((size_t)G * 4);

    hipMemsetAsync(cursor, 0, (size_t)NBIN * 4, stream);

    // CSR build: histogram+reserve+place, then per-bucket grouping
    bucketB_kernel<<<(E + TS - 1) / TS, 512, 0, stream>>>(ei, E, cursor, pairs);
    group_kernel<<<NB, 256, 0, stream>>>(pairs, cursor, x, N, dis, xp, rps, rpe, csr);

    // layer 1 fused: gather + GEMM + relu + scale -> hs (bf16)
    l1_kernel<<<(N + 255) / 256, 256, 0, stream>>>(rps, rpe, dis, csr, xp, W1, b1, hs, N);

    // layer 2 aggregation (barrier-free gather) -> aggz
    aggz_kernel<<<(N + 15) / 16, 256, 0, stream>>>(rps, rpe, csr, dis, (const uint4*)hs, aggz, N);

    // pool (1 wave/graph) + final GEMM (2 graphs/block, parallel)
    pool_kernel<<<(G + 3) / 4, 256, 0, stream>>>((const unsigned*)aggz, bat, pmean, pcnt, N, G);
    out_kernel<<<(G + 1) / 2, 256, 0, stream>>>(pmean, pcnt, W2, b2, out, G);
}